// Round 9
// baseline (362.463 us; speedup 1.0000x reference)
//
#include <hip/hip_runtime.h>
#include <hip/hip_bf16.h>
#include <cstdint>
#include <cstddef>

#define B_SZ   2
#define T_SEQ  2048
#define C_DIM  2048
#define NH     16
#define HD     128

typedef __attribute__((ext_vector_type(8))) short s8v;      // 8 bf16
typedef __attribute__((ext_vector_type(4))) float f32x4;

typedef __attribute__((address_space(3))) char lds_char;
typedef __attribute__((address_space(1))) const char glob_char;

// softmax runs in exp2 domain: q pre-scale folds 1/sqrt(HD) * log2(e)
#define QSCALE 0.12751887f   // 0.088388348 * 1.4426950

__device__ __forceinline__ unsigned short f2bf(float f) {
    union { float f; uint32_t i; } v; v.f = f;
    uint32_t r = (v.i + 0x7FFFu + ((v.i >> 16) & 1u)) >> 16;
    return (unsigned short)r;
}

// single-op RNE f32->bf16 via v_cvt_pk (low 16 bits used)
__device__ __forceinline__ unsigned short cvt1_bf16(float f) {
    unsigned int w;
    asm("v_cvt_pk_bf16_f32 %0, %1, %2" : "=v"(w) : "v"(f), "v"(f));
    return (unsigned short)w;
}

// DPP row-rotate move (within 16-lane rows) — VALU, no LDS traffic
template <int CTRL>
__device__ __forceinline__ float dpp_ror_f(float x) {
    int t = __builtin_amdgcn_update_dpp(__float_as_int(x), __float_as_int(x),
                                        CTRL, 0xf, 0xf, false);
    return __int_as_float(t);
}
// full 16-lane max reduce via rotate-reduce (4 DPP movs + 4 fmax)
__device__ __forceinline__ float rowmax16(float v) {
    v = fmaxf(v, dpp_ror_f<0x121>(v));   // ror:1
    v = fmaxf(v, dpp_ror_f<0x122>(v));   // ror:2
    v = fmaxf(v, dpp_ror_f<0x124>(v));   // ror:4
    v = fmaxf(v, dpp_ror_f<0x128>(v));   // ror:8
    return v;
}

// ---------------------------------------------------------------- convert x
__global__ void k_f32_to_bf16(const float* __restrict__ in,
                              unsigned short* __restrict__ out, int n4) {
    int i = blockIdx.x * blockDim.x + threadIdx.x;
    int stride = gridDim.x * blockDim.x;
    for (; i < n4; i += stride) {
        float4 v = reinterpret_cast<const float4*>(in)[i];
        ushort4 o;
        o.x = f2bf(v.x); o.y = f2bf(v.y); o.z = f2bf(v.z); o.w = f2bf(v.w);
        reinterpret_cast<ushort4*>(out)[i] = o;
    }
}

// ------------------------------------------------- transpose+convert weights
__global__ void k_transp_bf16(const float* __restrict__ in,
                              unsigned short* __restrict__ out,
                              int R, int C, int ldo) {
    __shared__ unsigned short tile[64][66];
    int x0 = blockIdx.x * 64, y0 = blockIdx.y * 64;
    int tx = threadIdx.x, ty = threadIdx.y;   // 64 x 4
#pragma unroll
    for (int j = 0; j < 16; ++j) {
        int r = y0 + ty + j * 4;
        tile[ty + j * 4][tx] = f2bf(in[(size_t)r * C + x0 + tx]);
    }
    __syncthreads();
#pragma unroll
    for (int j = 0; j < 16; ++j) {
        int orow = x0 + ty + j * 4;
        out[(size_t)orow * ldo + y0 + tx] = tile[tx][ty + j * 4];
    }
}

// ------------------------------------------------ rope tables (both layouts)
__global__ void k_rope_tab(float* __restrict__ cosT, float* __restrict__ sinT,
                           float* __restrict__ cosT2, float* __restrict__ sinT2) {
    int idx = blockIdx.x * blockDim.x + threadIdx.x;   // T*64
    if (idx >= T_SEQ * 64) return;
    int t = idx >> 6, i = idx & 63;
    float inv = powf(10000.0f, -(float)i / 64.0f);
    float ang = (float)t * inv;
    float c = cosf(ang), s = sinf(ang);
    cosT[idx] = c;  sinT[idx] = s;
    cosT2[i * T_SEQ + t] = c;  sinT2[i * T_SEQ + t] = s;
}

// ----------------------------------------------------------------- GEMM (BT)
#define BM 128
#define BN 128
#define BK 64

// generic 128x128 BT GEMM, 1-D grid with XCD-aware swizzle (nwg % 8 == 0)
__global__ __launch_bounds__(256) void k_gemm_bt(
        const unsigned short* __restrict__ A,
        const unsigned short* __restrict__ Bt,
        float* __restrict__ C, int M, int N, int K, int ldc, int gx) {
    __shared__ char smem[BM * BK * 2 + BN * BK * 2];   // 16KB A + 16KB B
    char* As = smem;
    char* Bs = smem + BM * BK * 2;
    int tid = threadIdx.x, lane = tid & 63, wid = tid >> 6;
    int nwg = gridDim.x, cpx = nwg >> 3;
    int orig = blockIdx.x;
    int wg = (orig & 7) * cpx + (orig >> 3);   // bijective: nwg % 8 == 0
    int bx = wg % gx, by = wg / gx;
    int m0 = by * BM, n0 = bx * BN;
    int wr = wid >> 1, wc = wid & 1;

    f32x4 acc[4][4] = {};

    int srow = wid * 32 + (lane >> 3);
    int cp = lane & 7;

    for (int k0 = 0; k0 < K; k0 += BK) {
#pragma unroll
        for (int i = 0; i < 4; ++i) {
            int row = srow + i * 8;
            int c = cp ^ (row & 7);
            const unsigned short* ga = A + (size_t)(m0 + row) * K + k0 + c * 8;
            const unsigned short* gb = Bt + (size_t)(n0 + row) * K + k0 + c * 8;
            __builtin_amdgcn_global_load_lds((glob_char*)ga,
                (lds_char*)(As + wid * 4096 + i * 1024), 16, 0, 0);
            __builtin_amdgcn_global_load_lds((glob_char*)gb,
                (lds_char*)(Bs + wid * 4096 + i * 1024), 16, 0, 0);
        }
        __syncthreads();

#pragma unroll
        for (int kc = 0; kc < 2; ++kc) {
            s8v af[4], bfr[4];
#pragma unroll
            for (int mi = 0; mi < 4; ++mi) {
                int row = wr * 64 + mi * 16 + (lane & 15);
                int slot = (kc * 4 + (lane >> 4)) ^ (row & 7);
                af[mi] = *reinterpret_cast<const s8v*>(As + row * 128 + slot * 16);
            }
#pragma unroll
            for (int ni = 0; ni < 4; ++ni) {
                int row = wc * 64 + ni * 16 + (lane & 15);
                int slot = (kc * 4 + (lane >> 4)) ^ (row & 7);
                bfr[ni] = *reinterpret_cast<const s8v*>(Bs + row * 128 + slot * 16);
            }
#pragma unroll
            for (int mi = 0; mi < 4; ++mi)
#pragma unroll
                for (int ni = 0; ni < 4; ++ni)
                    acc[mi][ni] = __builtin_amdgcn_mfma_f32_16x16x32_bf16(
                        af[mi], bfr[ni], acc[mi][ni], 0, 0, 0);
        }
        __syncthreads();
    }

#pragma unroll
    for (int mi = 0; mi < 4; ++mi) {
        int row = m0 + wr * 64 + mi * 16 + ((lane >> 4) << 2);
#pragma unroll
        for (int ni = 0; ni < 4; ++ni) {
            int col = n0 + wc * 64 + ni * 16 + (lane & 15);
            float* cp2 = C + (size_t)row * ldc + col;
#pragma unroll
            for (int r = 0; r < 4; ++r)
                cp2[(size_t)r * ldc] = acc[mi][ni][r];
        }
    }
}

// ------------------------- QKV GEMM with fused q-RoPE epilogue (4x1 waves)
__global__ __launch_bounds__(256) void k_gemm_qkv(
        const unsigned short* __restrict__ A,
        const unsigned short* __restrict__ Bt,
        const float* __restrict__ cosT2,
        const float* __restrict__ sinT2,
        unsigned short* __restrict__ qB,
        float* __restrict__ qkvKV) {
    const int GX = 18, K = 2048;
    __shared__ char smem[BM * BK * 2 + BN * BK * 2];
    char* As = smem;
    char* Bs = smem + BM * BK * 2;
    int tid = threadIdx.x, lane = tid & 63, wid = tid >> 6;
    int nwg = gridDim.x, cpx = nwg >> 3;       // 576 -> 72
    int orig = blockIdx.x;
    int wg = (orig & 7) * cpx + (orig >> 3);
    int bx = wg % GX, by = wg / GX;
    int m0 = by * BM, n0 = bx * BN;
    int l15 = lane & 15, l4 = lane >> 4;

    f32x4 acc[2][8] = {};

    int srow = wid * 32 + (lane >> 3);
    int cp = lane & 7;

    for (int k0 = 0; k0 < K; k0 += BK) {
#pragma unroll
        for (int i = 0; i < 4; ++i) {
            int row = srow + i * 8;
            int c = cp ^ (row & 7);
            const unsigned short* ga = A + (size_t)(m0 + row) * K + k0 + c * 8;
            const unsigned short* gb = Bt + (size_t)(n0 + row) * K + k0 + c * 8;
            __builtin_amdgcn_global_load_lds((glob_char*)ga,
                (lds_char*)(As + wid * 4096 + i * 1024), 16, 0, 0);
            __builtin_amdgcn_global_load_lds((glob_char*)gb,
                (lds_char*)(Bs + wid * 4096 + i * 1024), 16, 0, 0);
        }
        __syncthreads();

#pragma unroll
        for (int kc = 0; kc < 2; ++kc) {
            s8v af[2], bfr[8];
#pragma unroll
            for (int mi = 0; mi < 2; ++mi) {
                int row = wid * 32 + mi * 16 + l15;
                int slot = (kc * 4 + l4) ^ (row & 7);
                af[mi] = *reinterpret_cast<const s8v*>(As + row * 128 + slot * 16);
            }
#pragma unroll
            for (int ni = 0; ni < 8; ++ni) {
                int row = ni * 16 + l15;
                int slot = (kc * 4 + l4) ^ (row & 7);
                bfr[ni] = *reinterpret_cast<const s8v*>(Bs + row * 128 + slot * 16);
            }
#pragma unroll
            for (int mi = 0; mi < 2; ++mi)
#pragma unroll
                for (int ni = 0; ni < 8; ++ni)
                    acc[mi][ni] = __builtin_amdgcn_mfma_f32_16x16x32_bf16(
                        af[mi], bfr[ni], acc[mi][ni], 0, 0, 0);
        }
        __syncthreads();
    }

    if (bx < 16) {
        // fused RoPE + scale -> qB (b, h=bx, t, d) bf16
        int b = m0 >> 11, h = bx;
#pragma unroll
        for (int mi = 0; mi < 2; ++mi) {
            int t0 = (m0 + wid * 32 + mi * 16 + l4 * 4) & (T_SEQ - 1);
#pragma unroll
            for (int nip = 0; nip < 4; ++nip) {
                int d = nip * 16 + l15;
                float4 c4 = *reinterpret_cast<const float4*>(cosT2 + (size_t)d * T_SEQ + t0);
                float4 s4 = *reinterpret_cast<const float4*>(sinT2 + (size_t)d * T_SEQ + t0);
#pragma unroll
                for (int r = 0; r < 4; ++r) {
                    float x1 = acc[mi][nip][r];
                    float x2 = acc[mi][nip + 4][r];
                    float cc = (&c4.x)[r], ss = (&s4.x)[r];
                    float o1 = (x1 * cc - x2 * ss) * QSCALE;
                    float o2 = (x2 * cc + x1 * ss) * QSCALE;
                    size_t qoff = ((size_t)(b * NH + h) * T_SEQ + t0 + r) * HD + d;
                    qB[qoff] = cvt1_bf16(o1);
                    qB[qoff + 64] = cvt1_bf16(o2);
                }
            }
        }
    } else {
        // k/v columns -> compact f32 buffer (ld 256)
        int colb = (bx - 16) * 128;
#pragma unroll
        for (int mi = 0; mi < 2; ++mi) {
            int row = m0 + wid * 32 + mi * 16 + l4 * 4;
#pragma unroll
            for (int ni = 0; ni < 8; ++ni) {
                int col = colb + ni * 16 + l15;
                float* cp2 = qkvKV + (size_t)row * 256 + col;
#pragma unroll
                for (int r = 0; r < 4; ++r)
                    cp2[(size_t)r * 256] = acc[mi][ni][r];
            }
        }
    }
}

// -------------------------------------------- slim k/v transform + broadcast
__global__ void k_kv_transform(const float* __restrict__ qkvKV,
                               const float* __restrict__ cosT,
                               const float* __restrict__ sinT,
                               unsigned short* __restrict__ kB,
                               unsigned short* __restrict__ vT,
                               float* __restrict__ kexp,
                               float* __restrict__ vexp) {
    int bt = blockIdx.x;
    int b = bt >> 11, t = bt & 2047;
    int tid = threadIdx.x;
    const float* base = qkvKV + (size_t)bt * 256;

    if (tid < 64) {
        int d = tid;
        float c = cosT[t * 64 + d], s = sinT[t * 64 + d];
        float k1 = base[d], k2 = base[d + 64];
        float o1 = k1 * c - k2 * s;
        float o2 = k2 * c + k1 * s;
        size_t koff = ((size_t)b * T_SEQ + t) * HD + d;
        kB[koff] = f2bf(o1);
        kB[koff + 64] = f2bf(o2);
#pragma unroll
        for (int h = 0; h < NH; ++h) {
            size_t eoff = ((size_t)(b * NH + h) * T_SEQ + t) * HD + d;
            kexp[eoff] = o1;
            kexp[eoff + 64] = o2;
        }
    }
    if (tid >= 128) {
        int d = tid - 128;
        float v = base[128 + d];
        vT[((size_t)b * HD + d) * T_SEQ + t] = f2bf(v);
#pragma unroll
        for (int h = 0; h < NH; ++h)
            vexp[((size_t)(b * NH + h) * T_SEQ + t) * HD + d] = v;
    }
}

// ---------------------------------------------------------- flash attention
// v8: KVBLK=32, LDS 40KB -> 4 blocks/CU (4 waves/SIMD, 2x TLP vs v7).
// K dbuf 2x8K [32][128] swz ^(row&7); V^T dbuf 2x8K [128][64B] swz
// ^((row>>1)&3); P 4x2K [32][64B] swz ^(((row>>2)&3)<<4). Per-wave act
// guards skip fully-masked 32-kv tiles. Else identical to v7 math.
__global__ __launch_bounds__(256, 4) void k_flash_attn(
        const unsigned short* __restrict__ qB,
        const unsigned short* __restrict__ kB,
        const unsigned short* __restrict__ vT,
        unsigned short* __restrict__ yattn) {
    __shared__ char smem[40960];
    int tid = threadIdx.x, lane = tid & 63, wvid = tid >> 6;
    int l15 = lane & 15, l4 = lane >> 4;
    int blk = blockIdx.x;
    int b = blk >> 8;
    int rem = blk & 255;
    int h = rem & 15;
    int jj = rem >> 4;                 // 0..15
    int j0 = 16 + jj;                  // long unit (64-row q-tile index)
    int j1 = 15 - jj;                  // short unit
    int qrow0[2];
    qrow0[0] = j0 * 64 + wvid * 16;
    qrow0[1] = j1 * 64 + wvid * 16;

    char* Ks0 = smem;                  // 2 x 8192
    char* Vs0 = smem + 16384;          // 2 x 8192
    char* pbase = smem + 32768 + wvid * 2048;

    const unsigned short* kbB   = kB + (size_t)b * T_SEQ * HD;
    const unsigned short* vbase = vT + (size_t)b * HD * T_SEQ;

    s8v aq[2][4];
#pragma unroll
    for (int rt = 0; rt < 2; ++rt) {
        const unsigned short* qbase =
            qB + ((size_t)(b * NH + h) * T_SEQ + qrow0[rt]) * HD;
#pragma unroll
        for (int kc = 0; kc < 4; ++kc)
            aq[rt][kc] = *reinterpret_cast<const s8v*>(
                qbase + (size_t)l15 * HD + kc * 32 + l4 * 8);
    }

    float m_r[2][4], l_r[2][4];
#pragma unroll
    for (int rt = 0; rt < 2; ++rt)
#pragma unroll
        for (int r = 0; r < 4; ++r) { m_r[rt][r] = -3e38f; l_r[rt][r] = 0.f; }
    f32x4 o[2][8] = {};

    int NT = 2 * j0 + 2;   // 32-wide kv tiles for the long unit

    // stage 32-kv tile t: K 32x256B (8KB), V^T 128x64B (8KB)
    auto stage = [&](int buf, int t) {
        int kv0 = t * 32;
#pragma unroll
        for (int j = 0; j < 2; ++j) {
            int n = j * 256 + tid;            // K chunk 0..511
            int row = n >> 4, ch = n & 15;
            const unsigned short* src =
                kbB + (size_t)(kv0 + row) * HD + (ch ^ (row & 7)) * 8;
            __builtin_amdgcn_global_load_lds((glob_char*)src,
                (lds_char*)(Ks0 + buf * 8192 + j * 4096 + wvid * 1024), 16, 0, 0);
        }
#pragma unroll
        for (int j = 0; j < 2; ++j) {
            int n = j * 256 + tid;            // V chunk 0..511
            int row = n >> 2, ch = n & 3;     // 4 chunks per 64B row
            const unsigned short* src =
                vbase + (size_t)row * T_SEQ + kv0 + (ch ^ ((row >> 1) & 3)) * 8;
            __builtin_amdgcn_global_load_lds((glob_char*)src,
                (lds_char*)(Vs0 + buf * 8192 + j * 4096 + wvid * 1024), 16, 0, 0);
        }
    };

    stage(0, 0);
    asm volatile("s_waitcnt vmcnt(0)" ::: "memory");
    __builtin_amdgcn_s_barrier();
    __builtin_amdgcn_sched_barrier(0);

    for (int t = 0; t < NT; ++t) {
        int cur = t & 1;
        if (t + 1 < NT) stage(cur ^ 1, t + 1);   // prefetch under compute
        int kv0 = t * 32;
        const char* Kc = Ks0 + cur * 8192;
        const char* Vc = Vs0 + cur * 8192;
        int act[2];
        act[0] = (kv0 <= qrow0[0] + 15);         // per-wave: any unmasked row?
        act[1] = (kv0 <= qrow0[1] + 15);

        // ---- S = Q K^T (exp2-domain)
        f32x4 sfr[2][2] = {};
        __builtin_amdgcn_s_setprio(1);
#pragma unroll
        for (int kc = 0; kc < 4; ++kc) {
            s8v kf[2];
#pragma unroll
            for (int n = 0; n < 2; ++n) {
                int row = n * 16 + l15;
                int byte = row * 256 + ((kc * 64 + l4 * 16) ^ ((row & 7) << 4));
                kf[n] = *reinterpret_cast<const s8v*>(Kc + byte);
            }
            if (act[0]) {
#pragma unroll
                for (int n = 0; n < 2; ++n)
                    sfr[0][n] = __builtin_amdgcn_mfma_f32_16x16x32_bf16(
                        aq[0][kc], kf[n], sfr[0][n], 0, 0, 0);
            }
            if (act[1]) {
#pragma unroll
                for (int n = 0; n < 2; ++n)
                    sfr[1][n] = __builtin_amdgcn_mfma_f32_16x16x32_bf16(
                        aq[1][kc], kf[n], sfr[1][n], 0, 0, 0);
            }
        }
        __builtin_amdgcn_s_setprio(0);

        // ---- causal mask + online softmax per active rt
#pragma unroll
        for (int rt = 0; rt < 2; ++rt) {
            if (!act[rt]) continue;
            if (kv0 + 31 > qrow0[rt]) {
#pragma unroll
                for (int n = 0; n < 2; ++n)
#pragma unroll
                    for (int r = 0; r < 4; ++r) {
                        int col = kv0 + n * 16 + l15;
                        int row = qrow0[rt] + (l4 << 2) + r;
                        if (col > row) sfr[rt][n][r] = -1e9f;
                    }
            }
            float pm[4];
#pragma unroll
            for (int r = 0; r < 4; ++r) {
                float v0 = fmaxf(sfr[rt][0][r], sfr[rt][1][r]);
                pm[r] = rowmax16(v0);
            }
            int ok = (pm[0] <= m_r[rt][0] + 8.0f) &
                     (pm[1] <= m_r[rt][1] + 8.0f) &
                     (pm[2] <= m_r[rt][2] + 8.0f) &
                     (pm[3] <= m_r[rt][3] + 8.0f);
            if (!__all(ok)) {
#pragma unroll
                for (int r = 0; r < 4; ++r) {
                    float mn = fmaxf(m_r[rt][r], pm[r]);
                    float al = exp2f(m_r[rt][r] - mn);
                    l_r[rt][r] *= al;
#pragma unroll
                    for (int ds = 0; ds < 8; ++ds)
                        o[rt][ds][r] *= al;
                    m_r[rt][r] = mn;
                }
            }
#pragma unroll
            for (int n = 0; n < 2; ++n)
#pragma unroll
                for (int r = 0; r < 4; ++r) {
                    float p = exp2f(sfr[rt][n][r] - m_r[rt][r]);
                    sfr[rt][n][r] = p;
                    l_r[rt][r] += p;
                }
        }

        // ---- P -> wave-private LDS ([32 rows][64B], swz ^(((row>>2)&3)<<4))
#pragma unroll
        for (int rt = 0; rt < 2; ++rt) {
            if (!act[rt]) continue;
#pragma unroll
            for (int n = 0; n < 2; ++n)
#pragma unroll
                for (int r = 0; r < 4; ++r) {
                    int rowl = rt * 16 + (l4 << 2) + r;
                    int byte = rowl * 64 +
                        (((n * 16 + l15) * 2) ^ (((rowl >> 2) & 3) << 4));
                    *reinterpret_cast<unsigned short*>(pbase + byte) =
                        cvt1_bf16(sfr[rt][n][r]);
                }
        }
        asm volatile("s_waitcnt lgkmcnt(0)" ::: "memory");
        __builtin_amdgcn_sched_barrier(0);

        // ---- O += P V
        __builtin_amdgcn_s_setprio(1);
        {
            s8v pa[2];
#pragma unroll
            for (int rt = 0; rt < 2; ++rt) {
                int rowl = rt * 16 + l15;
                int byte = rowl * 64 + ((l4 * 16) ^ (((rowl >> 2) & 3) << 4));
                pa[rt] = *reinterpret_cast<const s8v*>(pbase + byte);
            }
#pragma unroll
            for (int ds = 0; ds < 8; ++ds) {
                int vrow = ds * 16 + l15;
                int vbyte = vrow * 64 + ((l4 * 16) ^ (((vrow >> 1) & 3) << 4));
                s8v bv = *reinterpret_cast<const s8v*>(Vc + vbyte);
                if (act[0])
                    o[0][ds] = __builtin_amdgcn_mfma_f32_16x16x32_bf16(
                        pa[0], bv, o[0][ds], 0, 0, 0);
                if (act[1])
                    o[1][ds] = __builtin_amdgcn_mfma_f32_16x16x32_bf16(
                        pa[1], bv, o[1][ds], 0, 0, 0);
            }
        }
        __builtin_amdgcn_s_setprio(0);

        // ---- tile end: prefetch drained (flew under compute), LDS reads done
        asm volatile("s_waitcnt vmcnt(0) lgkmcnt(0)" ::: "memory");
        __builtin_amdgcn_s_barrier();
        __builtin_amdgcn_sched_barrier(0);
    }

    // ---- epilogue: reduce l across 16-lane row groups (once), normalize
#pragma unroll
    for (int rt = 0; rt < 2; ++rt) {
        float inv[4];
#pragma unroll
        for (int r = 0; r < 4; ++r) {
            float lv = l_r[rt][r];
#pragma unroll
            for (int off = 1; off < 16; off <<= 1)
                lv += __shfl_xor(lv, off);
            inv[r] = 1.0f / lv;
        }
#pragma unroll
        for (int ds = 0; ds < 8; ++ds)
#pragma unroll
            for (int r = 0; r < 4; ++r) {
                int row = qrow0[rt] + (l4 << 2) + r;
                int col = h * HD + ds * 16 + l15;
                yattn[((size_t)b * T_SEQ + row) * C_DIM + col] =
                    cvt1_bf16(o[rt][ds][r] * inv[r]);
            }
    }
}

// ---------------------------------------------------------------------------
extern "C" void kernel_launch(void* const* d_in, const int* in_sizes, int n_in,
                              void* d_out, int out_size, void* d_ws, size_t ws_size,
                              hipStream_t stream) {
    const float* x  = (const float*)d_in[0];
    // d_in[1] = attn_mask (fixed causal -1e9 triu; implemented analytically)
    const float* wq = (const float*)d_in[2];
    const float* wk = (const float*)d_in[3];
    const float* wv = (const float*)d_in[4];
    const float* wo = (const float*)d_in[5];

    char* ws = (char*)d_ws;
    size_t off = 0;
    auto alloc = [&](size_t bytes) -> void* {
        void* p = ws + off;
        off += (bytes + 255) & ~(size_t)255;
        return p;
    };
    unsigned short* xb    = (unsigned short*)alloc((size_t)4096 * 2048 * 2);
    unsigned short* wT    = (unsigned short*)alloc((size_t)2304 * 2048 * 2);
    unsigned short* woT   = (unsigned short*)alloc((size_t)2048 * 2048 * 2);
    float*          qkvKV = (float*)alloc((size_t)4096 * 256 * 4);
    float*          cosT  = (float*)alloc((size_t)2048 * 64 * 4);
    float*          sinT  = (float*)alloc((size_t)2048 * 64 * 4);
    float*          cosT2 = (float*)alloc((size_t)64 * 2048 * 4);
    float*          sinT2 = (float*)alloc((size_t)64 * 2048 * 4);
    unsigned short* qB    = (unsigned short*)alloc((size_t)2 * 16 * 2048 * 128 * 2);
    unsigned short* kB    = (unsigned short*)alloc((size_t)2 * 2048 * 128 * 2);
    unsigned short* vT    = (unsigned short*)alloc((size_t)2 * 128 * 2048 * 2);
    unsigned short* yattn = (unsigned short*)alloc((size_t)4096 * 2048 * 2);

    float* y_out = (float*)d_out;
    float* kexp  = y_out + (size_t)2 * 2048 * 2048;
    float* vexp  = kexp + (size_t)2 * 16 * 2048 * 128;

    dim3 tb(64, 4);
    k_f32_to_bf16<<<2048, 256, 0, stream>>>(x, xb, 4096 * 2048 / 4);
    k_transp_bf16<<<dim3(32, 32), tb, 0, stream>>>(wq, wT, 2048, 2048, 2048);
    k_transp_bf16<<<dim3(2, 32), tb, 0, stream>>>(wk, wT + (size_t)2048 * 2048, 2048, 128, 2048);
    k_transp_bf16<<<dim3(2, 32), tb, 0, stream>>>(wv, wT + (size_t)2176 * 2048, 2048, 128, 2048);
    k_transp_bf16<<<dim3(32, 32), tb, 0, stream>>>(wo, woT, 2048, 2048, 2048);
    k_rope_tab<<<512, 256, 0, stream>>>(cosT, sinT, cosT2, sinT2);

    k_gemm_qkv<<<576, 256, 0, stream>>>(xb, wT, cosT2, sinT2, qB, qkvKV);
    k_kv_transform<<<4096, 256, 0, stream>>>(qkvKV, cosT, sinT, kB, vT, kexp, vexp);
    k_flash_attn<<<512, 256, 0, stream>>>(qB, kB, vT, yattn);
    k_gemm_bt<<<512, 256, 0, stream>>>(
        yattn, woT, y_out, 4096, 2048, 2048, 2048, 16);
}

// Round 10
// 249.251 us; speedup vs baseline: 1.4542x; 1.4542x over previous
//
#include <hip/hip_runtime.h>
#include <hip/hip_bf16.h>
#include <cstdint>
#include <cstddef>

#define B_SZ   2
#define T_SEQ  2048
#define C_DIM  2048
#define NH     16
#define HD     128

typedef __attribute__((ext_vector_type(8))) short s8v;      // 8 bf16
typedef __attribute__((ext_vector_type(4))) float f32x4;

typedef __attribute__((address_space(3))) char lds_char;
typedef __attribute__((address_space(1))) const char glob_char;

// softmax runs in exp2 domain: q pre-scale folds 1/sqrt(HD) * log2(e)
#define QSCALE 0.12751887f   // 0.088388348 * 1.4426950

__device__ __forceinline__ unsigned short f2bf(float f) {
    union { float f; uint32_t i; } v; v.f = f;
    uint32_t r = (v.i + 0x7FFFu + ((v.i >> 16) & 1u)) >> 16;
    return (unsigned short)r;
}

// single-op RNE f32->bf16 via v_cvt_pk (low 16 bits used)
__device__ __forceinline__ unsigned short cvt1_bf16(float f) {
    unsigned int w;
    asm("v_cvt_pk_bf16_f32 %0, %1, %2" : "=v"(w) : "v"(f), "v"(f));
    return (unsigned short)w;
}

// DPP row-rotate move (within 16-lane rows) — VALU, no LDS traffic
template <int CTRL>
__device__ __forceinline__ float dpp_ror_f(float x) {
    int t = __builtin_amdgcn_update_dpp(__float_as_int(x), __float_as_int(x),
                                        CTRL, 0xf, 0xf, false);
    return __int_as_float(t);
}
// full 16-lane max reduce via rotate-reduce (4 DPP movs + 4 fmax)
__device__ __forceinline__ float rowmax16(float v) {
    v = fmaxf(v, dpp_ror_f<0x121>(v));   // ror:1
    v = fmaxf(v, dpp_ror_f<0x122>(v));   // ror:2
    v = fmaxf(v, dpp_ror_f<0x124>(v));   // ror:4
    v = fmaxf(v, dpp_ror_f<0x128>(v));   // ror:8
    return v;
}

// ---------------------------------------------------------------- convert x
__global__ void k_f32_to_bf16(const float* __restrict__ in,
                              unsigned short* __restrict__ out, int n4) {
    int i = blockIdx.x * blockDim.x + threadIdx.x;
    int stride = gridDim.x * blockDim.x;
    for (; i < n4; i += stride) {
        float4 v = reinterpret_cast<const float4*>(in)[i];
        ushort4 o;
        o.x = f2bf(v.x); o.y = f2bf(v.y); o.z = f2bf(v.z); o.w = f2bf(v.w);
        reinterpret_cast<ushort4*>(out)[i] = o;
    }
}

// ------------------------------------------------- transpose+convert weights
__global__ void k_transp_bf16(const float* __restrict__ in,
                              unsigned short* __restrict__ out,
                              int R, int C, int ldo) {
    __shared__ unsigned short tile[64][66];
    int x0 = blockIdx.x * 64, y0 = blockIdx.y * 64;
    int tx = threadIdx.x, ty = threadIdx.y;   // 64 x 4
#pragma unroll
    for (int j = 0; j < 16; ++j) {
        int r = y0 + ty + j * 4;
        tile[ty + j * 4][tx] = f2bf(in[(size_t)r * C + x0 + tx]);
    }
    __syncthreads();
#pragma unroll
    for (int j = 0; j < 16; ++j) {
        int orow = x0 + ty + j * 4;
        out[(size_t)orow * ldo + y0 + tx] = tile[tx][ty + j * 4];
    }
}

// ------------------------------------------------ rope tables (both layouts)
__global__ void k_rope_tab(float* __restrict__ cosT, float* __restrict__ sinT,
                           float* __restrict__ cosT2, float* __restrict__ sinT2) {
    int idx = blockIdx.x * blockDim.x + threadIdx.x;   // T*64
    if (idx >= T_SEQ * 64) return;
    int t = idx >> 6, i = idx & 63;
    float inv = powf(10000.0f, -(float)i / 64.0f);
    float ang = (float)t * inv;
    float c = cosf(ang), s = sinf(ang);
    cosT[idx] = c;  sinT[idx] = s;
    cosT2[i * T_SEQ + t] = c;  sinT2[i * T_SEQ + t] = s;
}

// ----------------------------------------------------------------- GEMM (BT)
#define BM 128
#define BN 128
#define BK 64

// generic 128x128 BT GEMM, 1-D grid with XCD-aware swizzle (nwg % 8 == 0)
__global__ __launch_bounds__(256) void k_gemm_bt(
        const unsigned short* __restrict__ A,
        const unsigned short* __restrict__ Bt,
        float* __restrict__ C, int M, int N, int K, int ldc, int gx) {
    __shared__ char smem[BM * BK * 2 + BN * BK * 2];   // 16KB A + 16KB B
    char* As = smem;
    char* Bs = smem + BM * BK * 2;
    int tid = threadIdx.x, lane = tid & 63, wid = tid >> 6;
    int nwg = gridDim.x, cpx = nwg >> 3;
    int orig = blockIdx.x;
    int wg = (orig & 7) * cpx + (orig >> 3);   // bijective: nwg % 8 == 0
    int bx = wg % gx, by = wg / gx;
    int m0 = by * BM, n0 = bx * BN;
    int wr = wid >> 1, wc = wid & 1;

    f32x4 acc[4][4] = {};

    int srow = wid * 32 + (lane >> 3);
    int cp = lane & 7;

    for (int k0 = 0; k0 < K; k0 += BK) {
#pragma unroll
        for (int i = 0; i < 4; ++i) {
            int row = srow + i * 8;
            int c = cp ^ (row & 7);
            const unsigned short* ga = A + (size_t)(m0 + row) * K + k0 + c * 8;
            const unsigned short* gb = Bt + (size_t)(n0 + row) * K + k0 + c * 8;
            __builtin_amdgcn_global_load_lds((glob_char*)ga,
                (lds_char*)(As + wid * 4096 + i * 1024), 16, 0, 0);
            __builtin_amdgcn_global_load_lds((glob_char*)gb,
                (lds_char*)(Bs + wid * 4096 + i * 1024), 16, 0, 0);
        }
        __syncthreads();

#pragma unroll
        for (int kc = 0; kc < 2; ++kc) {
            s8v af[4], bfr[4];
#pragma unroll
            for (int mi = 0; mi < 4; ++mi) {
                int row = wr * 64 + mi * 16 + (lane & 15);
                int slot = (kc * 4 + (lane >> 4)) ^ (row & 7);
                af[mi] = *reinterpret_cast<const s8v*>(As + row * 128 + slot * 16);
            }
#pragma unroll
            for (int ni = 0; ni < 4; ++ni) {
                int row = wc * 64 + ni * 16 + (lane & 15);
                int slot = (kc * 4 + (lane >> 4)) ^ (row & 7);
                bfr[ni] = *reinterpret_cast<const s8v*>(Bs + row * 128 + slot * 16);
            }
#pragma unroll
            for (int mi = 0; mi < 4; ++mi)
#pragma unroll
                for (int ni = 0; ni < 4; ++ni)
                    acc[mi][ni] = __builtin_amdgcn_mfma_f32_16x16x32_bf16(
                        af[mi], bfr[ni], acc[mi][ni], 0, 0, 0);
        }
        __syncthreads();
    }

#pragma unroll
    for (int mi = 0; mi < 4; ++mi) {
        int row = m0 + wr * 64 + mi * 16 + ((lane >> 4) << 2);
#pragma unroll
        for (int ni = 0; ni < 4; ++ni) {
            int col = n0 + wc * 64 + ni * 16 + (lane & 15);
            float* cp2 = C + (size_t)row * ldc + col;
#pragma unroll
            for (int r = 0; r < 4; ++r)
                cp2[(size_t)r * ldc] = acc[mi][ni][r];
        }
    }
}

// ------------------------- QKV GEMM with fused q-RoPE epilogue (4x1 waves)
__global__ __launch_bounds__(256) void k_gemm_qkv(
        const unsigned short* __restrict__ A,
        const unsigned short* __restrict__ Bt,
        const float* __restrict__ cosT2,
        const float* __restrict__ sinT2,
        unsigned short* __restrict__ qB,
        float* __restrict__ qkvKV) {
    const int GX = 18, K = 2048;
    __shared__ char smem[BM * BK * 2 + BN * BK * 2];
    char* As = smem;
    char* Bs = smem + BM * BK * 2;
    int tid = threadIdx.x, lane = tid & 63, wid = tid >> 6;
    int nwg = gridDim.x, cpx = nwg >> 3;       // 576 -> 72
    int orig = blockIdx.x;
    int wg = (orig & 7) * cpx + (orig >> 3);
    int bx = wg % GX, by = wg / GX;
    int m0 = by * BM, n0 = bx * BN;
    int l15 = lane & 15, l4 = lane >> 4;

    f32x4 acc[2][8] = {};

    int srow = wid * 32 + (lane >> 3);
    int cp = lane & 7;

    for (int k0 = 0; k0 < K; k0 += BK) {
#pragma unroll
        for (int i = 0; i < 4; ++i) {
            int row = srow + i * 8;
            int c = cp ^ (row & 7);
            const unsigned short* ga = A + (size_t)(m0 + row) * K + k0 + c * 8;
            const unsigned short* gb = Bt + (size_t)(n0 + row) * K + k0 + c * 8;
            __builtin_amdgcn_global_load_lds((glob_char*)ga,
                (lds_char*)(As + wid * 4096 + i * 1024), 16, 0, 0);
            __builtin_amdgcn_global_load_lds((glob_char*)gb,
                (lds_char*)(Bs + wid * 4096 + i * 1024), 16, 0, 0);
        }
        __syncthreads();

#pragma unroll
        for (int kc = 0; kc < 2; ++kc) {
            s8v af[2], bfr[8];
#pragma unroll
            for (int mi = 0; mi < 2; ++mi) {
                int row = wid * 32 + mi * 16 + l15;
                int slot = (kc * 4 + l4) ^ (row & 7);
                af[mi] = *reinterpret_cast<const s8v*>(As + row * 128 + slot * 16);
            }
#pragma unroll
            for (int ni = 0; ni < 8; ++ni) {
                int row = ni * 16 + l15;
                int slot = (kc * 4 + l4) ^ (row & 7);
                bfr[ni] = *reinterpret_cast<const s8v*>(Bs + row * 128 + slot * 16);
            }
#pragma unroll
            for (int mi = 0; mi < 2; ++mi)
#pragma unroll
                for (int ni = 0; ni < 8; ++ni)
                    acc[mi][ni] = __builtin_amdgcn_mfma_f32_16x16x32_bf16(
                        af[mi], bfr[ni], acc[mi][ni], 0, 0, 0);
        }
        __syncthreads();
    }

    if (bx < 16) {
        // fused RoPE + scale -> qB (b, h=bx, t, d) bf16
        int b = m0 >> 11, h = bx;
#pragma unroll
        for (int mi = 0; mi < 2; ++mi) {
            int t0 = (m0 + wid * 32 + mi * 16 + l4 * 4) & (T_SEQ - 1);
#pragma unroll
            for (int nip = 0; nip < 4; ++nip) {
                int d = nip * 16 + l15;
                float4 c4 = *reinterpret_cast<const float4*>(cosT2 + (size_t)d * T_SEQ + t0);
                float4 s4 = *reinterpret_cast<const float4*>(sinT2 + (size_t)d * T_SEQ + t0);
#pragma unroll
                for (int r = 0; r < 4; ++r) {
                    float x1 = acc[mi][nip][r];
                    float x2 = acc[mi][nip + 4][r];
                    float cc = (&c4.x)[r], ss = (&s4.x)[r];
                    float o1 = (x1 * cc - x2 * ss) * QSCALE;
                    float o2 = (x2 * cc + x1 * ss) * QSCALE;
                    size_t qoff = ((size_t)(b * NH + h) * T_SEQ + t0 + r) * HD + d;
                    qB[qoff] = cvt1_bf16(o1);
                    qB[qoff + 64] = cvt1_bf16(o2);
                }
            }
        }
    } else {
        // k/v columns -> compact f32 buffer (ld 256)
        int colb = (bx - 16) * 128;
#pragma unroll
        for (int mi = 0; mi < 2; ++mi) {
            int row = m0 + wid * 32 + mi * 16 + l4 * 4;
#pragma unroll
            for (int ni = 0; ni < 8; ++ni) {
                int col = colb + ni * 16 + l15;
                float* cp2 = qkvKV + (size_t)row * 256 + col;
#pragma unroll
                for (int r = 0; r < 4; ++r)
                    cp2[(size_t)r * 256] = acc[mi][ni][r];
            }
        }
    }
}

// -------------------------------------------- slim k/v transform + broadcast
__global__ void k_kv_transform(const float* __restrict__ qkvKV,
                               const float* __restrict__ cosT,
                               const float* __restrict__ sinT,
                               unsigned short* __restrict__ kB,
                               unsigned short* __restrict__ vT,
                               float* __restrict__ kexp,
                               float* __restrict__ vexp) {
    int bt = blockIdx.x;
    int b = bt >> 11, t = bt & 2047;
    int tid = threadIdx.x;
    const float* base = qkvKV + (size_t)bt * 256;

    if (tid < 64) {
        int d = tid;
        float c = cosT[t * 64 + d], s = sinT[t * 64 + d];
        float k1 = base[d], k2 = base[d + 64];
        float o1 = k1 * c - k2 * s;
        float o2 = k2 * c + k1 * s;
        size_t koff = ((size_t)b * T_SEQ + t) * HD + d;
        kB[koff] = f2bf(o1);
        kB[koff + 64] = f2bf(o2);
#pragma unroll
        for (int h = 0; h < NH; ++h) {
            size_t eoff = ((size_t)(b * NH + h) * T_SEQ + t) * HD + d;
            kexp[eoff] = o1;
            kexp[eoff + 64] = o2;
        }
    }
    if (tid >= 128) {
        int d = tid - 128;
        float v = base[128 + d];
        vT[((size_t)b * HD + d) * T_SEQ + t] = f2bf(v);
#pragma unroll
        for (int h = 0; h < NH; ++h)
            vexp[((size_t)(b * NH + h) * T_SEQ + t) * HD + d] = v;
    }
}

// ---------------------------------------------------------- flash attention
// v10 = v7 revert (proven 91 us, 128 VGPR, no spill). R9's 4-waves/SIMD
// attempt spilled (VGPR capped 64, WRITE_SIZE 63MB scratch) — the ~130-VGPR
// per-wave state admits at most 2-3 waves/SIMD; keep launch_bounds(256,2).
__global__ __launch_bounds__(256, 2) void k_flash_attn(
        const unsigned short* __restrict__ qB,
        const unsigned short* __restrict__ kB,
        const unsigned short* __restrict__ vT,
        unsigned short* __restrict__ yattn) {
    __shared__ char smem[81920];   // K dbuf 32K | V dbuf 32K | P 4x4K
    int tid = threadIdx.x, lane = tid & 63, wvid = tid >> 6;
    int blk = blockIdx.x;
    int b = blk >> 8;
    int rem = blk & 255;
    int h = rem & 15;
    int jj = rem >> 4;                 // 0..15
    int j0 = 16 + jj;                  // long unit (64-row q-tile index)
    int j1 = 15 - jj;                  // short unit
    int qrow0[2];
    qrow0[0] = j0 * 64 + wvid * 16;
    qrow0[1] = j1 * 64 + wvid * 16;

    char* Ks0 = smem;
    char* Vs0 = smem + 32768;
    char* pbase = smem + 65536 + wvid * 4096;

    const unsigned short* kbB   = kB + (size_t)b * T_SEQ * HD;
    const unsigned short* vbase = vT + (size_t)b * HD * T_SEQ;

    s8v aq[2][4];
#pragma unroll
    for (int rt = 0; rt < 2; ++rt) {
        const unsigned short* qbase =
            qB + ((size_t)(b * NH + h) * T_SEQ + qrow0[rt]) * HD;
#pragma unroll
        for (int kc = 0; kc < 4; ++kc)
            aq[rt][kc] = *reinterpret_cast<const s8v*>(
                qbase + (size_t)(lane & 15) * HD + kc * 32 + (lane >> 4) * 8);
    }

    float m_r[2][4], l_r[2][4];
#pragma unroll
    for (int rt = 0; rt < 2; ++rt)
#pragma unroll
        for (int r = 0; r < 4; ++r) { m_r[rt][r] = -3e38f; l_r[rt][r] = 0.f; }
    f32x4 o[2][8] = {};

    int NT = j0 + 1;

    auto stage = [&](int buf, int t) {
        int kv0 = t * 64;
#pragma unroll
        for (int j = 0; j < 4; ++j) {
            int n = j * 256 + tid;
            int row = n >> 4, ch = n & 15;
            const unsigned short* src =
                kbB + (size_t)(kv0 + row) * HD + (ch ^ (row & 7)) * 8;
            __builtin_amdgcn_global_load_lds((glob_char*)src,
                (lds_char*)(Ks0 + buf * 16384 + j * 4096 + wvid * 1024), 16, 0, 0);
        }
#pragma unroll
        for (int j = 0; j < 4; ++j) {
            int n = j * 256 + tid;
            int row = n >> 3, ch = n & 7;
            const unsigned short* src =
                vbase + (size_t)row * T_SEQ + kv0 + (ch ^ (row & 7)) * 8;
            __builtin_amdgcn_global_load_lds((glob_char*)src,
                (lds_char*)(Vs0 + buf * 16384 + j * 4096 + wvid * 1024), 16, 0, 0);
        }
    };

    stage(0, 0);
    asm volatile("s_waitcnt vmcnt(0)" ::: "memory");
    __builtin_amdgcn_s_barrier();
    __builtin_amdgcn_sched_barrier(0);

    for (int t = 0; t < NT; ++t) {
        int cur = t & 1;
        if (t + 1 < NT) stage(cur ^ 1, t + 1);
        int kv0 = t * 64;
        const char* Kc = Ks0 + cur * 16384;
        const char* Vc = Vs0 + cur * 16384;
        int act1 = (t <= j1);

        f32x4 sfr[2][4] = {};
        __builtin_amdgcn_s_setprio(1);
#pragma unroll
        for (int kc = 0; kc < 4; ++kc) {
            s8v kf[4];
#pragma unroll
            for (int n = 0; n < 4; ++n) {
                int row = n * 16 + (lane & 15);
                int byte = row * 256 +
                    ((kc * 64 + (lane >> 4) * 16) ^ ((row & 7) << 4));
                kf[n] = *reinterpret_cast<const s8v*>(Kc + byte);
            }
#pragma unroll
            for (int n = 0; n < 4; ++n)
                sfr[0][n] = __builtin_amdgcn_mfma_f32_16x16x32_bf16(
                    aq[0][kc], kf[n], sfr[0][n], 0, 0, 0);
            if (act1) {
#pragma unroll
                for (int n = 0; n < 4; ++n)
                    sfr[1][n] = __builtin_amdgcn_mfma_f32_16x16x32_bf16(
                        aq[1][kc], kf[n], sfr[1][n], 0, 0, 0);
            }
        }
        __builtin_amdgcn_s_setprio(0);

#pragma unroll
        for (int rt = 0; rt < 2; ++rt) {
            if (rt == 1 && !act1) continue;
            if (kv0 + 63 > qrow0[rt]) {
#pragma unroll
                for (int n = 0; n < 4; ++n)
#pragma unroll
                    for (int r = 0; r < 4; ++r) {
                        int col = kv0 + n * 16 + (lane & 15);
                        int row = qrow0[rt] + ((lane >> 4) << 2) + r;
                        if (col > row) sfr[rt][n][r] = -1e9f;
                    }
            }
            float pm[4];
#pragma unroll
            for (int r = 0; r < 4; ++r) {
                float v0 = fmaxf(fmaxf(sfr[rt][0][r], sfr[rt][1][r]),
                                 fmaxf(sfr[rt][2][r], sfr[rt][3][r]));
                pm[r] = rowmax16(v0);
            }
            int ok = (pm[0] <= m_r[rt][0] + 8.0f) &
                     (pm[1] <= m_r[rt][1] + 8.0f) &
                     (pm[2] <= m_r[rt][2] + 8.0f) &
                     (pm[3] <= m_r[rt][3] + 8.0f);
            if (!__all(ok)) {
#pragma unroll
                for (int r = 0; r < 4; ++r) {
                    float mn = fmaxf(m_r[rt][r], pm[r]);
                    float al = exp2f(m_r[rt][r] - mn);
                    l_r[rt][r] *= al;
#pragma unroll
                    for (int ds = 0; ds < 8; ++ds)
                        o[rt][ds][r] *= al;
                    m_r[rt][r] = mn;
                }
            }
#pragma unroll
            for (int n = 0; n < 4; ++n)
#pragma unroll
                for (int r = 0; r < 4; ++r) {
                    float p = exp2f(sfr[rt][n][r] - m_r[rt][r]);
                    sfr[rt][n][r] = p;
                    l_r[rt][r] += p;
                }
        }

#pragma unroll
        for (int rt = 0; rt < 2; ++rt) {
            if (rt == 1 && !act1) continue;
#pragma unroll
            for (int n = 0; n < 4; ++n)
#pragma unroll
                for (int r = 0; r < 4; ++r) {
                    int rowl = rt * 16 + ((lane >> 4) << 2) + r;
                    int byte = rowl * 128 + (n * 16 + (lane & 15)) * 2;
                    byte ^= ((rowl & 7) << 4);
                    *reinterpret_cast<unsigned short*>(pbase + byte) =
                        cvt1_bf16(sfr[rt][n][r]);
                }
        }
        asm volatile("s_waitcnt lgkmcnt(0)" ::: "memory");
        __builtin_amdgcn_sched_barrier(0);

        __builtin_amdgcn_s_setprio(1);
#pragma unroll
        for (int kc2 = 0; kc2 < 2; ++kc2) {
            s8v pa[2];
#pragma unroll
            for (int rt = 0; rt < 2; ++rt) {
                int rowl = rt * 16 + (lane & 15);
                int byte = rowl * 128 +
                    ((kc2 * 64 + (lane >> 4) * 16) ^ ((rowl & 7) << 4));
                pa[rt] = *reinterpret_cast<const s8v*>(pbase + byte);
            }
#pragma unroll
            for (int ds = 0; ds < 8; ++ds) {
                int vrow = ds * 16 + (lane & 15);
                int vbyte = vrow * 128 +
                    ((kc2 * 64 + (lane >> 4) * 16) ^ ((vrow & 7) << 4));
                s8v bv = *reinterpret_cast<const s8v*>(Vc + vbyte);
                o[0][ds] = __builtin_amdgcn_mfma_f32_16x16x32_bf16(
                    pa[0], bv, o[0][ds], 0, 0, 0);
                if (act1)
                    o[1][ds] = __builtin_amdgcn_mfma_f32_16x16x32_bf16(
                        pa[1], bv, o[1][ds], 0, 0, 0);
            }
        }
        __builtin_amdgcn_s_setprio(0);

        asm volatile("s_waitcnt vmcnt(0) lgkmcnt(0)" ::: "memory");
        __builtin_amdgcn_s_barrier();
        __builtin_amdgcn_sched_barrier(0);
    }

#pragma unroll
    for (int rt = 0; rt < 2; ++rt) {
        float inv[4];
#pragma unroll
        for (int r = 0; r < 4; ++r) {
            float lv = l_r[rt][r];
#pragma unroll
            for (int off = 1; off < 16; off <<= 1)
                lv += __shfl_xor(lv, off);
            inv[r] = 1.0f / lv;
        }
#pragma unroll
        for (int ds = 0; ds < 8; ++ds)
#pragma unroll
            for (int r = 0; r < 4; ++r) {
                int row = qrow0[rt] + ((lane >> 4) << 2) + r;
                int col = h * HD + ds * 16 + (lane & 15);
                yattn[((size_t)b * T_SEQ + row) * C_DIM + col] =
                    cvt1_bf16(o[rt][ds][r] * inv[r]);
            }
    }
}

// ---------------------------------------------------------------------------
extern "C" void kernel_launch(void* const* d_in, const int* in_sizes, int n_in,
                              void* d_out, int out_size, void* d_ws, size_t ws_size,
                              hipStream_t stream) {
    const float* x  = (const float*)d_in[0];
    // d_in[1] = attn_mask (fixed causal -1e9 triu; implemented analytically)
    const float* wq = (const float*)d_in[2];
    const float* wk = (const float*)d_in[3];
    const float* wv = (const float*)d_in[4];
    const float* wo = (const float*)d_in[5];

    char* ws = (char*)d_ws;
    size_t off = 0;
    auto alloc = [&](size_t bytes) -> void* {
        void* p = ws + off;
        off += (bytes + 255) & ~(size_t)255;
        return p;
    };
    unsigned short* xb    = (unsigned short*)alloc((size_t)4096 * 2048 * 2);
    unsigned short* wT    = (unsigned short*)alloc((size_t)2304 * 2048 * 2);
    unsigned short* woT   = (unsigned short*)alloc((size_t)2048 * 2048 * 2);
    float*          qkvKV = (float*)alloc((size_t)4096 * 256 * 4);
    float*          cosT  = (float*)alloc((size_t)2048 * 64 * 4);
    float*          sinT  = (float*)alloc((size_t)2048 * 64 * 4);
    float*          cosT2 = (float*)alloc((size_t)64 * 2048 * 4);
    float*          sinT2 = (float*)alloc((size_t)64 * 2048 * 4);
    unsigned short* qB    = (unsigned short*)alloc((size_t)2 * 16 * 2048 * 128 * 2);
    unsigned short* kB    = (unsigned short*)alloc((size_t)2 * 2048 * 128 * 2);
    unsigned short* vT    = (unsigned short*)alloc((size_t)2 * 128 * 2048 * 2);
    unsigned short* yattn = (unsigned short*)alloc((size_t)4096 * 2048 * 2);

    float* y_out = (float*)d_out;
    float* kexp  = y_out + (size_t)2 * 2048 * 2048;
    float* vexp  = kexp + (size_t)2 * 16 * 2048 * 128;

    dim3 tb(64, 4);
    k_f32_to_bf16<<<2048, 256, 0, stream>>>(x, xb, 4096 * 2048 / 4);
    k_transp_bf16<<<dim3(32, 32), tb, 0, stream>>>(wq, wT, 2048, 2048, 2048);
    k_transp_bf16<<<dim3(2, 32), tb, 0, stream>>>(wk, wT + (size_t)2048 * 2048, 2048, 128, 2048);
    k_transp_bf16<<<dim3(2, 32), tb, 0, stream>>>(wv, wT + (size_t)2176 * 2048, 2048, 128, 2048);
    k_transp_bf16<<<dim3(32, 32), tb, 0, stream>>>(wo, woT, 2048, 2048, 2048);
    k_rope_tab<<<512, 256, 0, stream>>>(cosT, sinT, cosT2, sinT2);

    k_gemm_qkv<<<576, 256, 0, stream>>>(xb, wT, cosT2, sinT2, qB, qkvKV);
    k_kv_transform<<<4096, 256, 0, stream>>>(qkvKV, cosT, sinT, kB, vT, kexp, vexp);
    k_flash_attn<<<512, 256, 0, stream>>>(qB, kB, vT, yattn);
    k_gemm_bt<<<512, 256, 0, stream>>>(
        yattn, woT, y_out, 4096, 2048, 2048, 2048, 16);
}

// Round 11
// 248.760 us; speedup vs baseline: 1.4571x; 1.0020x over previous
//
#include <hip/hip_runtime.h>
#include <hip/hip_bf16.h>
#include <cstdint>
#include <cstddef>

#define B_SZ   2
#define T_SEQ  2048
#define C_DIM  2048
#define NH     16
#define HD     128

typedef __attribute__((ext_vector_type(8))) short s8v;      // 8 bf16
typedef __attribute__((ext_vector_type(4))) float f32x4;

typedef __attribute__((address_space(3))) char lds_char;
typedef __attribute__((address_space(1))) const char glob_char;

// softmax runs in exp2 domain: q pre-scale folds 1/sqrt(HD) * log2(e)
#define QSCALE 0.12751887f   // 0.088388348 * 1.4426950

__device__ __forceinline__ unsigned short f2bf(float f) {
    union { float f; uint32_t i; } v; v.f = f;
    uint32_t r = (v.i + 0x7FFFu + ((v.i >> 16) & 1u)) >> 16;
    return (unsigned short)r;
}

// single-op RNE f32->bf16 via v_cvt_pk (low 16 bits used)
__device__ __forceinline__ unsigned short cvt1_bf16(float f) {
    unsigned int w;
    asm("v_cvt_pk_bf16_f32 %0, %1, %2" : "=v"(w) : "v"(f), "v"(f));
    return (unsigned short)w;
}

// DPP row-rotate move (within 16-lane rows) — VALU, no LDS traffic
template <int CTRL>
__device__ __forceinline__ float dpp_ror_f(float x) {
    int t = __builtin_amdgcn_update_dpp(__float_as_int(x), __float_as_int(x),
                                        CTRL, 0xf, 0xf, false);
    return __int_as_float(t);
}
// full 16-lane max reduce via rotate-reduce (4 DPP movs + 4 fmax)
__device__ __forceinline__ float rowmax16(float v) {
    v = fmaxf(v, dpp_ror_f<0x121>(v));   // ror:1
    v = fmaxf(v, dpp_ror_f<0x122>(v));   // ror:2
    v = fmaxf(v, dpp_ror_f<0x124>(v));   // ror:4
    v = fmaxf(v, dpp_ror_f<0x128>(v));   // ror:8
    return v;
}

// ---------------------------------------------------------------- convert x
__global__ void k_f32_to_bf16(const float* __restrict__ in,
                              unsigned short* __restrict__ out, int n4) {
    int i = blockIdx.x * blockDim.x + threadIdx.x;
    int stride = gridDim.x * blockDim.x;
    for (; i < n4; i += stride) {
        float4 v = reinterpret_cast<const float4*>(in)[i];
        ushort4 o;
        o.x = f2bf(v.x); o.y = f2bf(v.y); o.z = f2bf(v.z); o.w = f2bf(v.w);
        reinterpret_cast<ushort4*>(out)[i] = o;
    }
}

// ------------------------------------------------- transpose+convert weights
__global__ void k_transp_bf16(const float* __restrict__ in,
                              unsigned short* __restrict__ out,
                              int R, int C, int ldo) {
    __shared__ unsigned short tile[64][66];
    int x0 = blockIdx.x * 64, y0 = blockIdx.y * 64;
    int tx = threadIdx.x, ty = threadIdx.y;   // 64 x 4
#pragma unroll
    for (int j = 0; j < 16; ++j) {
        int r = y0 + ty + j * 4;
        tile[ty + j * 4][tx] = f2bf(in[(size_t)r * C + x0 + tx]);
    }
    __syncthreads();
#pragma unroll
    for (int j = 0; j < 16; ++j) {
        int orow = x0 + ty + j * 4;
        out[(size_t)orow * ldo + y0 + tx] = tile[tx][ty + j * 4];
    }
}

// ------------------------------------------------ rope tables (both layouts)
__global__ void k_rope_tab(float* __restrict__ cosT, float* __restrict__ sinT,
                           float* __restrict__ cosT2, float* __restrict__ sinT2) {
    int idx = blockIdx.x * blockDim.x + threadIdx.x;   // T*64
    if (idx >= T_SEQ * 64) return;
    int t = idx >> 6, i = idx & 63;
    float inv = powf(10000.0f, -(float)i / 64.0f);
    float ang = (float)t * inv;
    float c = cosf(ang), s = sinf(ang);
    cosT[idx] = c;  sinT[idx] = s;
    cosT2[i * T_SEQ + t] = c;  sinT2[i * T_SEQ + t] = s;
}

// ----------------------------------------------------------------- GEMM (BT)
#define BM 128
#define BN 128
#define BK 64

// generic 128x128 BT GEMM, 1-D grid with XCD-aware swizzle (nwg % 8 == 0)
__global__ __launch_bounds__(256) void k_gemm_bt(
        const unsigned short* __restrict__ A,
        const unsigned short* __restrict__ Bt,
        float* __restrict__ C, int M, int N, int K, int ldc, int gx) {
    __shared__ char smem[BM * BK * 2 + BN * BK * 2];   // 16KB A + 16KB B
    char* As = smem;
    char* Bs = smem + BM * BK * 2;
    int tid = threadIdx.x, lane = tid & 63, wid = tid >> 6;
    int nwg = gridDim.x, cpx = nwg >> 3;
    int orig = blockIdx.x;
    int wg = (orig & 7) * cpx + (orig >> 3);   // bijective: nwg % 8 == 0
    int bx = wg % gx, by = wg / gx;
    int m0 = by * BM, n0 = bx * BN;
    int wr = wid >> 1, wc = wid & 1;

    f32x4 acc[4][4] = {};

    int srow = wid * 32 + (lane >> 3);
    int cp = lane & 7;

    for (int k0 = 0; k0 < K; k0 += BK) {
#pragma unroll
        for (int i = 0; i < 4; ++i) {
            int row = srow + i * 8;
            int c = cp ^ (row & 7);
            const unsigned short* ga = A + (size_t)(m0 + row) * K + k0 + c * 8;
            const unsigned short* gb = Bt + (size_t)(n0 + row) * K + k0 + c * 8;
            __builtin_amdgcn_global_load_lds((glob_char*)ga,
                (lds_char*)(As + wid * 4096 + i * 1024), 16, 0, 0);
            __builtin_amdgcn_global_load_lds((glob_char*)gb,
                (lds_char*)(Bs + wid * 4096 + i * 1024), 16, 0, 0);
        }
        __syncthreads();

#pragma unroll
        for (int kc = 0; kc < 2; ++kc) {
            s8v af[4], bfr[4];
#pragma unroll
            for (int mi = 0; mi < 4; ++mi) {
                int row = wr * 64 + mi * 16 + (lane & 15);
                int slot = (kc * 4 + (lane >> 4)) ^ (row & 7);
                af[mi] = *reinterpret_cast<const s8v*>(As + row * 128 + slot * 16);
            }
#pragma unroll
            for (int ni = 0; ni < 4; ++ni) {
                int row = wc * 64 + ni * 16 + (lane & 15);
                int slot = (kc * 4 + (lane >> 4)) ^ (row & 7);
                bfr[ni] = *reinterpret_cast<const s8v*>(Bs + row * 128 + slot * 16);
            }
#pragma unroll
            for (int mi = 0; mi < 4; ++mi)
#pragma unroll
                for (int ni = 0; ni < 4; ++ni)
                    acc[mi][ni] = __builtin_amdgcn_mfma_f32_16x16x32_bf16(
                        af[mi], bfr[ni], acc[mi][ni], 0, 0, 0);
        }
        __syncthreads();
    }

#pragma unroll
    for (int mi = 0; mi < 4; ++mi) {
        int row = m0 + wr * 64 + mi * 16 + ((lane >> 4) << 2);
#pragma unroll
        for (int ni = 0; ni < 4; ++ni) {
            int col = n0 + wc * 64 + ni * 16 + (lane & 15);
            float* cp2 = C + (size_t)row * ldc + col;
#pragma unroll
            for (int r = 0; r < 4; ++r)
                cp2[(size_t)r * ldc] = acc[mi][ni][r];
        }
    }
}

// ------------------------- QKV GEMM with fused q-RoPE epilogue (4x1 waves)
__global__ __launch_bounds__(256) void k_gemm_qkv(
        const unsigned short* __restrict__ A,
        const unsigned short* __restrict__ Bt,
        const float* __restrict__ cosT2,
        const float* __restrict__ sinT2,
        unsigned short* __restrict__ qB,
        float* __restrict__ qkvKV) {
    const int GX = 18, K = 2048;
    __shared__ char smem[BM * BK * 2 + BN * BK * 2];
    char* As = smem;
    char* Bs = smem + BM * BK * 2;
    int tid = threadIdx.x, lane = tid & 63, wid = tid >> 6;
    int nwg = gridDim.x, cpx = nwg >> 3;       // 576 -> 72
    int orig = blockIdx.x;
    int wg = (orig & 7) * cpx + (orig >> 3);
    int bx = wg % GX, by = wg / GX;
    int m0 = by * BM, n0 = bx * BN;
    int l15 = lane & 15, l4 = lane >> 4;

    f32x4 acc[2][8] = {};

    int srow = wid * 32 + (lane >> 3);
    int cp = lane & 7;

    for (int k0 = 0; k0 < K; k0 += BK) {
#pragma unroll
        for (int i = 0; i < 4; ++i) {
            int row = srow + i * 8;
            int c = cp ^ (row & 7);
            const unsigned short* ga = A + (size_t)(m0 + row) * K + k0 + c * 8;
            const unsigned short* gb = Bt + (size_t)(n0 + row) * K + k0 + c * 8;
            __builtin_amdgcn_global_load_lds((glob_char*)ga,
                (lds_char*)(As + wid * 4096 + i * 1024), 16, 0, 0);
            __builtin_amdgcn_global_load_lds((glob_char*)gb,
                (lds_char*)(Bs + wid * 4096 + i * 1024), 16, 0, 0);
        }
        __syncthreads();

#pragma unroll
        for (int kc = 0; kc < 2; ++kc) {
            s8v af[2], bfr[8];
#pragma unroll
            for (int mi = 0; mi < 2; ++mi) {
                int row = wid * 32 + mi * 16 + l15;
                int slot = (kc * 4 + l4) ^ (row & 7);
                af[mi] = *reinterpret_cast<const s8v*>(As + row * 128 + slot * 16);
            }
#pragma unroll
            for (int ni = 0; ni < 8; ++ni) {
                int row = ni * 16 + l15;
                int slot = (kc * 4 + l4) ^ (row & 7);
                bfr[ni] = *reinterpret_cast<const s8v*>(Bs + row * 128 + slot * 16);
            }
#pragma unroll
            for (int mi = 0; mi < 2; ++mi)
#pragma unroll
                for (int ni = 0; ni < 8; ++ni)
                    acc[mi][ni] = __builtin_amdgcn_mfma_f32_16x16x32_bf16(
                        af[mi], bfr[ni], acc[mi][ni], 0, 0, 0);
        }
        __syncthreads();
    }

    if (bx < 16) {
        // fused RoPE + scale -> qB (b, h=bx, t, d) bf16
        int b = m0 >> 11, h = bx;
#pragma unroll
        for (int mi = 0; mi < 2; ++mi) {
            int t0 = (m0 + wid * 32 + mi * 16 + l4 * 4) & (T_SEQ - 1);
#pragma unroll
            for (int nip = 0; nip < 4; ++nip) {
                int d = nip * 16 + l15;
                float4 c4 = *reinterpret_cast<const float4*>(cosT2 + (size_t)d * T_SEQ + t0);
                float4 s4 = *reinterpret_cast<const float4*>(sinT2 + (size_t)d * T_SEQ + t0);
#pragma unroll
                for (int r = 0; r < 4; ++r) {
                    float x1 = acc[mi][nip][r];
                    float x2 = acc[mi][nip + 4][r];
                    float cc = (&c4.x)[r], ss = (&s4.x)[r];
                    float o1 = (x1 * cc - x2 * ss) * QSCALE;
                    float o2 = (x2 * cc + x1 * ss) * QSCALE;
                    size_t qoff = ((size_t)(b * NH + h) * T_SEQ + t0 + r) * HD + d;
                    qB[qoff] = cvt1_bf16(o1);
                    qB[qoff + 64] = cvt1_bf16(o2);
                }
            }
        }
    } else {
        // k/v columns -> compact f32 buffer (ld 256)
        int colb = (bx - 16) * 128;
#pragma unroll
        for (int mi = 0; mi < 2; ++mi) {
            int row = m0 + wid * 32 + mi * 16 + l4 * 4;
#pragma unroll
            for (int ni = 0; ni < 8; ++ni) {
                int col = colb + ni * 16 + l15;
                float* cp2 = qkvKV + (size_t)row * 256 + col;
#pragma unroll
                for (int r = 0; r < 4; ++r)
                    cp2[(size_t)r * 256] = acc[mi][ni][r];
            }
        }
    }
}

// -------------------------------------------- slim k/v transform + broadcast
__global__ void k_kv_transform(const float* __restrict__ qkvKV,
                               const float* __restrict__ cosT,
                               const float* __restrict__ sinT,
                               unsigned short* __restrict__ kB,
                               unsigned short* __restrict__ vT,
                               float* __restrict__ kexp,
                               float* __restrict__ vexp) {
    int bt = blockIdx.x;
    int b = bt >> 11, t = bt & 2047;
    int tid = threadIdx.x;
    const float* base = qkvKV + (size_t)bt * 256;

    if (tid < 64) {
        int d = tid;
        float c = cosT[t * 64 + d], s = sinT[t * 64 + d];
        float k1 = base[d], k2 = base[d + 64];
        float o1 = k1 * c - k2 * s;
        float o2 = k2 * c + k1 * s;
        size_t koff = ((size_t)b * T_SEQ + t) * HD + d;
        kB[koff] = f2bf(o1);
        kB[koff + 64] = f2bf(o2);
#pragma unroll
        for (int h = 0; h < NH; ++h) {
            size_t eoff = ((size_t)(b * NH + h) * T_SEQ + t) * HD + d;
            kexp[eoff] = o1;
            kexp[eoff + 64] = o2;
        }
    }
    if (tid >= 128) {
        int d = tid - 128;
        float v = base[128 + d];
        vT[((size_t)b * HD + d) * T_SEQ + t] = f2bf(v);
#pragma unroll
        for (int h = 0; h < NH; ++h)
            vexp[((size_t)(b * NH + h) * T_SEQ + t) * HD + d] = v;
    }
}

// ---------------------------------------------------------- flash attention
// v11: 1024 blocks (b,h,u-unit), 4 waves x 16 q-rows, KVBLK=32.
// LDS 36KB -> 4 blocks/CU; grid 4 blocks/CU -> 16 waves/CU (2x TLP vs v7).
// Per-wave state ~100 VGPR (no R9-style 2-unit pairing -> no spill at
// launch_bounds(256,4)). u-permutation: each CU's 4 round-robin blocks sum
// to 62 tile-units, heavy-first. Swizzles carried from correctness-proven
// R9 kernel; math pipeline (exp2, defer-max, DPP rowmax, lazy-l) unchanged.
__global__ __launch_bounds__(256, 4) void k_flash_attn(
        const unsigned short* __restrict__ qB,
        const unsigned short* __restrict__ kB,
        const unsigned short* __restrict__ vT,
        unsigned short* __restrict__ yattn) {
    __shared__ char smem[36864];   // K dbuf 16K | V dbuf 16K | P 4x1K
    int tid = threadIdx.x, lane = tid & 63, wvid = tid >> 6;
    int l15 = lane & 15, l4 = lane >> 4;
    int blk = blockIdx.x;
    int bh = blk & 31;
    int b = bh >> 4, h = bh & 15;
    int g = blk >> 5;                  // 0..31
    int a = g & 7, qq = g >> 3;
    int u = (qq == 0) ? (31 - a) : (qq == 1) ? (16 + a)
          : (qq == 2) ? (15 - a) : a;          // per-CU sum = 62, heavy first
    int qrow0 = u * 64 + wvid * 16;

    char* Ks0 = smem;                  // 2 x 8192
    char* Vs0 = smem + 16384;          // 2 x 8192
    char* pbase = smem + 32768 + wvid * 1024;

    const unsigned short* kbB   = kB + (size_t)b * T_SEQ * HD;
    const unsigned short* vbase = vT + (size_t)b * HD * T_SEQ;

    // Q fragments: 16 rows, 4 k-chunks, register-resident
    const unsigned short* qbase =
        qB + ((size_t)(b * NH + h) * T_SEQ + qrow0) * HD;
    s8v aq[4];
#pragma unroll
    for (int kc = 0; kc < 4; ++kc)
        aq[kc] = *reinterpret_cast<const s8v*>(
            qbase + (size_t)l15 * HD + kc * 32 + l4 * 8);

    float m_r[4], l_r[4];
#pragma unroll
    for (int r = 0; r < 4; ++r) { m_r[r] = -3e38f; l_r[r] = 0.f; }
    f32x4 o[8] = {};

    int NT = 2 * u + 2;   // 32-wide kv tiles

    // stage 32-kv tile t: K 32x256B (8KB), V^T 128x64B (8KB)
    auto stage = [&](int buf, int t) {
        int kv0 = t * 32;
#pragma unroll
        for (int j = 0; j < 2; ++j) {
            int n = j * 256 + tid;            // K chunk 0..511
            int row = n >> 4, ch = n & 15;
            const unsigned short* src =
                kbB + (size_t)(kv0 + row) * HD + (ch ^ (row & 7)) * 8;
            __builtin_amdgcn_global_load_lds((glob_char*)src,
                (lds_char*)(Ks0 + buf * 8192 + j * 4096 + wvid * 1024), 16, 0, 0);
        }
#pragma unroll
        for (int j = 0; j < 2; ++j) {
            int n = j * 256 + tid;            // V chunk 0..511
            int row = n >> 2, ch = n & 3;     // 4 chunks per 64B row
            const unsigned short* src =
                vbase + (size_t)row * T_SEQ + kv0 + (ch ^ ((row >> 1) & 3)) * 8;
            __builtin_amdgcn_global_load_lds((glob_char*)src,
                (lds_char*)(Vs0 + buf * 8192 + j * 4096 + wvid * 1024), 16, 0, 0);
        }
    };

    stage(0, 0);
    asm volatile("s_waitcnt vmcnt(0)" ::: "memory");
    __builtin_amdgcn_s_barrier();
    __builtin_amdgcn_sched_barrier(0);

    for (int t = 0; t < NT; ++t) {
        int cur = t & 1;
        if (t + 1 < NT) stage(cur ^ 1, t + 1);   // prefetch under compute
        int kv0 = t * 32;
        const char* Kc = Ks0 + cur * 8192;
        const char* Vc = Vs0 + cur * 8192;
        int act = (kv0 <= qrow0 + 15);           // any unmasked row for wave?

        if (act) {
            // ---- S = Q K^T (exp2-domain)
            f32x4 sfr[2] = {};
            __builtin_amdgcn_s_setprio(1);
#pragma unroll
            for (int kc = 0; kc < 4; ++kc) {
                s8v kf[2];
#pragma unroll
                for (int n = 0; n < 2; ++n) {
                    int row = n * 16 + l15;
                    int byte = row * 256 +
                        ((kc * 64 + l4 * 16) ^ ((row & 7) << 4));
                    kf[n] = *reinterpret_cast<const s8v*>(Kc + byte);
                }
#pragma unroll
                for (int n = 0; n < 2; ++n)
                    sfr[n] = __builtin_amdgcn_mfma_f32_16x16x32_bf16(
                        aq[kc], kf[n], sfr[n], 0, 0, 0);
            }
            __builtin_amdgcn_s_setprio(0);

            // ---- causal mask (partial tiles only)
            if (kv0 + 31 > qrow0) {
#pragma unroll
                for (int n = 0; n < 2; ++n)
#pragma unroll
                    for (int r = 0; r < 4; ++r) {
                        int col = kv0 + n * 16 + l15;
                        int row = qrow0 + (l4 << 2) + r;
                        if (col > row) sfr[n][r] = -1e9f;
                    }
            }

            // ---- online softmax (exp2; defer-max THR=8; lazy l)
            float pm[4];
#pragma unroll
            for (int r = 0; r < 4; ++r)
                pm[r] = rowmax16(fmaxf(sfr[0][r], sfr[1][r]));
            int ok = (pm[0] <= m_r[0] + 8.0f) & (pm[1] <= m_r[1] + 8.0f) &
                     (pm[2] <= m_r[2] + 8.0f) & (pm[3] <= m_r[3] + 8.0f);
            if (!__all(ok)) {
#pragma unroll
                for (int r = 0; r < 4; ++r) {
                    float mn = fmaxf(m_r[r], pm[r]);
                    float al = exp2f(m_r[r] - mn);
                    l_r[r] *= al;
#pragma unroll
                    for (int ds = 0; ds < 8; ++ds)
                        o[ds][r] *= al;
                    m_r[r] = mn;
                }
            }
#pragma unroll
            for (int n = 0; n < 2; ++n)
#pragma unroll
                for (int r = 0; r < 4; ++r) {
                    float p = exp2f(sfr[n][r] - m_r[r]);
                    sfr[n][r] = p;
                    l_r[r] += p;
                }

            // ---- P -> wave-private LDS ([16 rows][64B], swz ^((row^(row>>2))&3)<<4)
#pragma unroll
            for (int n = 0; n < 2; ++n)
#pragma unroll
                for (int r = 0; r < 4; ++r) {
                    int rowl = (l4 << 2) + r;
                    int byte = rowl * 64 +
                        (((n * 16 + l15) * 2) ^ (((rowl ^ (rowl >> 2)) & 3) << 4));
                    *reinterpret_cast<unsigned short*>(pbase + byte) =
                        cvt1_bf16(sfr[n][r]);
                }
        }
        asm volatile("s_waitcnt lgkmcnt(0)" ::: "memory");
        __builtin_amdgcn_sched_barrier(0);

        // ---- O += P V
        if (act) {
            __builtin_amdgcn_s_setprio(1);
            int rowl = l15;
            int byte = rowl * 64 +
                ((l4 * 16) ^ (((rowl ^ (rowl >> 2)) & 3) << 4));
            s8v pa = *reinterpret_cast<const s8v*>(pbase + byte);
#pragma unroll
            for (int ds = 0; ds < 8; ++ds) {
                int vrow = ds * 16 + l15;
                int vbyte = vrow * 64 + ((l4 * 16) ^ (((vrow >> 1) & 3) << 4));
                s8v bv = *reinterpret_cast<const s8v*>(Vc + vbyte);
                o[ds] = __builtin_amdgcn_mfma_f32_16x16x32_bf16(
                    pa, bv, o[ds], 0, 0, 0);
            }
            __builtin_amdgcn_s_setprio(0);
        }

        // ---- tile end: prefetch drained (flew under compute), LDS reads done
        asm volatile("s_waitcnt vmcnt(0) lgkmcnt(0)" ::: "memory");
        __builtin_amdgcn_s_barrier();
        __builtin_amdgcn_sched_barrier(0);
    }

    // ---- epilogue: reduce l across 16-lane row groups (once), normalize
    float inv[4];
#pragma unroll
    for (int r = 0; r < 4; ++r) {
        float lv = l_r[r];
#pragma unroll
        for (int off = 1; off < 16; off <<= 1)
            lv += __shfl_xor(lv, off);
        inv[r] = 1.0f / lv;
    }
#pragma unroll
    for (int ds = 0; ds < 8; ++ds)
#pragma unroll
        for (int r = 0; r < 4; ++r) {
            int row = qrow0 + (l4 << 2) + r;
            int col = h * HD + ds * 16 + l15;
            yattn[((size_t)b * T_SEQ + row) * C_DIM + col] =
                cvt1_bf16(o[ds][r] * inv[r]);
        }
}

// ---------------------------------------------------------------------------
extern "C" void kernel_launch(void* const* d_in, const int* in_sizes, int n_in,
                              void* d_out, int out_size, void* d_ws, size_t ws_size,
                              hipStream_t stream) {
    const float* x  = (const float*)d_in[0];
    // d_in[1] = attn_mask (fixed causal -1e9 triu; implemented analytically)
    const float* wq = (const float*)d_in[2];
    const float* wk = (const float*)d_in[3];
    const float* wv = (const float*)d_in[4];
    const float* wo = (const float*)d_in[5];

    char* ws = (char*)d_ws;
    size_t off = 0;
    auto alloc = [&](size_t bytes) -> void* {
        void* p = ws + off;
        off += (bytes + 255) & ~(size_t)255;
        return p;
    };
    unsigned short* xb    = (unsigned short*)alloc((size_t)4096 * 2048 * 2);
    unsigned short* wT    = (unsigned short*)alloc((size_t)2304 * 2048 * 2);
    unsigned short* woT   = (unsigned short*)alloc((size_t)2048 * 2048 * 2);
    float*          qkvKV = (float*)alloc((size_t)4096 * 256 * 4);
    float*          cosT  = (float*)alloc((size_t)2048 * 64 * 4);
    float*          sinT  = (float*)alloc((size_t)2048 * 64 * 4);
    float*          cosT2 = (float*)alloc((size_t)64 * 2048 * 4);
    float*          sinT2 = (float*)alloc((size_t)64 * 2048 * 4);
    unsigned short* qB    = (unsigned short*)alloc((size_t)2 * 16 * 2048 * 128 * 2);
    unsigned short* kB    = (unsigned short*)alloc((size_t)2 * 2048 * 128 * 2);
    unsigned short* vT    = (unsigned short*)alloc((size_t)2 * 128 * 2048 * 2);
    unsigned short* yattn = (unsigned short*)alloc((size_t)4096 * 2048 * 2);

    float* y_out = (float*)d_out;
    float* kexp  = y_out + (size_t)2 * 2048 * 2048;
    float* vexp  = kexp + (size_t)2 * 16 * 2048 * 128;

    dim3 tb(64, 4);
    k_f32_to_bf16<<<2048, 256, 0, stream>>>(x, xb, 4096 * 2048 / 4);
    k_transp_bf16<<<dim3(32, 32), tb, 0, stream>>>(wq, wT, 2048, 2048, 2048);
    k_transp_bf16<<<dim3(2, 32), tb, 0, stream>>>(wk, wT + (size_t)2048 * 2048, 2048, 128, 2048);
    k_transp_bf16<<<dim3(2, 32), tb, 0, stream>>>(wv, wT + (size_t)2176 * 2048, 2048, 128, 2048);
    k_transp_bf16<<<dim3(32, 32), tb, 0, stream>>>(wo, woT, 2048, 2048, 2048);
    k_rope_tab<<<512, 256, 0, stream>>>(cosT, sinT, cosT2, sinT2);

    k_gemm_qkv<<<576, 256, 0, stream>>>(xb, wT, cosT2, sinT2, qB, qkvKV);
    k_kv_transform<<<4096, 256, 0, stream>>>(qkvKV, cosT, sinT, kB, vT, kexp, vexp);
    k_flash_attn<<<1024, 256, 0, stream>>>(qB, kB, vT, yattn);
    k_gemm_bt<<<512, 256, 0, stream>>>(
        yattn, woT, y_out, 4096, 2048, 2048, 2048, 16);
}